// Round 1
// baseline (25654.010 us; speedup 1.0000x reference)
//
#include <hip/hip_runtime.h>
#include <hip/hip_bf16.h>
#include <cstdio>

typedef __hip_bfloat16 bf16;
typedef __attribute__((ext_vector_type(8))) short bf16x8;
typedef __attribute__((ext_vector_type(4))) float f32x4;

constexpr int NB = 64, NT = 256, NIN = 4096, NHID = 1024, NHEAD = 8, NHD = 128;
constexpr int NLAYER = 2, NKT = 64, NKEYS = 322, NOUT = 12;

__device__ __forceinline__ float bf2f(bf16 v) { return __bfloat162float(v); }
__device__ __forceinline__ bf16 f2bf(float v) { return __float2bfloat16(v); }

__device__ __forceinline__ void gload16(const void* g, void* l) {
  __builtin_amdgcn_global_load_lds((const __attribute__((address_space(1))) void*)g,
                                   (__attribute__((address_space(3))) void*)l, 16, 0, 0);
}

// ---------------- GEMM: C[M,N] = A[M,K] @ W[N,K]^T + bias, optional relu ----
// OMODE: 0 = f32 out, 1 = bf16 out, 2 = both.  M%128==0, N%128==0, K%32==0.
template <int OMODE, bool RELU>
__global__ __launch_bounds__(256) void gemm_bt(
    const bf16* __restrict__ A, const bf16* __restrict__ W,
    const float* __restrict__ bias, float* __restrict__ Cf,
    bf16* __restrict__ Cb, int M, int N, int K) {
  __shared__ bf16 As[128 * 32];
  __shared__ bf16 Bs[128 * 32];
  const int tid = threadIdx.x;
  const int wave = tid >> 6, lane = tid & 63;
  const int m0 = blockIdx.x * 128, n0 = blockIdx.y * 128;
  const int wm = (wave >> 1) * 64, wn = (wave & 1) * 64;
  const int lr = lane >> 4, lc = lane & 15;

  f32x4 acc[4][4];
#pragma unroll
  for (int i = 0; i < 4; ++i)
#pragma unroll
    for (int j = 0; j < 4; ++j) acc[i][j] = (f32x4){0.f, 0.f, 0.f, 0.f};

  for (int k0 = 0; k0 < K; k0 += 32) {
#pragma unroll
    for (int j = 0; j < 2; ++j) {
      const int c = (wave * 2 + j) * 64 + lane;     // chunk 0..511
      const int row = c >> 2, kq = (c & 3) * 8;     // 4 chunks/row of 64B
      gload16(A + (size_t)(m0 + row) * K + k0 + kq, (char*)As + (size_t)(wave * 2 + j) * 1024);
      gload16(W + (size_t)(n0 + row) * K + k0 + kq, (char*)Bs + (size_t)(wave * 2 + j) * 1024);
    }
    __syncthreads();  // drains global_load_lds (vmcnt0 before barrier)
    bf16x8 af[4], bv[4];
#pragma unroll
    for (int mi = 0; mi < 4; ++mi)
      af[mi] = *(const bf16x8*)(As + (wm + mi * 16 + lc) * 32 + lr * 8);
#pragma unroll
    for (int ni = 0; ni < 4; ++ni)
      bv[ni] = *(const bf16x8*)(Bs + (wn + ni * 16 + lc) * 32 + lr * 8);
#pragma unroll
    for (int mi = 0; mi < 4; ++mi)
#pragma unroll
      for (int ni = 0; ni < 4; ++ni)
        acc[mi][ni] = __builtin_amdgcn_mfma_f32_16x16x32_bf16(af[mi], bv[ni], acc[mi][ni], 0, 0, 0);
    __syncthreads();
  }

#pragma unroll
  for (int mi = 0; mi < 4; ++mi)
#pragma unroll
    for (int ni = 0; ni < 4; ++ni) {
      const int col = n0 + wn + ni * 16 + lc;
      const float bb = bias[col];
#pragma unroll
      for (int i = 0; i < 4; ++i) {
        const int row = m0 + wm + mi * 16 + lr * 4 + i;
        float v = acc[mi][ni][i] + bb;
        if (RELU) v = fmaxf(v, 0.f);
        if constexpr (OMODE == 0 || OMODE == 2) Cf[(size_t)row * N + col] = v;
        if constexpr (OMODE == 1 || OMODE == 2) Cb[(size_t)row * N + col] = f2bf(v);
      }
    }
}

// ---------------- LayerNorm (one block per row) -----------------------------
template <int DIM, bool RES, bool OUTBF>
__global__ __launch_bounds__(256) void ln_kernel(
    const float* __restrict__ X, const float* __restrict__ R,
    const float* __restrict__ g, const float* __restrict__ bt,
    bf16* __restrict__ ob, float* __restrict__ of) {
  constexpr int PT = DIM / 1024;  // float4s per thread
  const int row = blockIdx.x, tid = threadIdx.x;
  const float4* xr = (const float4*)(X + (size_t)row * DIM);
  float4 v[PT];
  float s = 0.f, sq = 0.f;
#pragma unroll
  for (int j = 0; j < PT; ++j) {
    v[j] = xr[tid + j * 256];
    if constexpr (RES) {
      const float4 r4 = ((const float4*)(R + (size_t)row * DIM))[tid + j * 256];
      v[j].x += r4.x; v[j].y += r4.y; v[j].z += r4.z; v[j].w += r4.w;
    }
    s += v[j].x + v[j].y + v[j].z + v[j].w;
    sq += v[j].x * v[j].x + v[j].y * v[j].y + v[j].z * v[j].z + v[j].w * v[j].w;
  }
#pragma unroll
  for (int o = 32; o; o >>= 1) { s += __shfl_down(s, o); sq += __shfl_down(sq, o); }
  __shared__ float red[8];
  const int wave = tid >> 6, lane = tid & 63;
  if (!lane) { red[wave] = s; red[wave + 4] = sq; }
  __syncthreads();
  s = red[0] + red[1] + red[2] + red[3];
  sq = red[4] + red[5] + red[6] + red[7];
  const float mean = s * (1.f / DIM);
  const float var = sq * (1.f / DIM) - mean * mean;
  const float rs = rsqrtf(var + 1e-5f);
#pragma unroll
  for (int j = 0; j < PT; ++j) {
    const int c = (tid + j * 256) * 4;
    const float o0 = (v[j].x - mean) * rs * g[c + 0] + bt[c + 0];
    const float o1 = (v[j].y - mean) * rs * g[c + 1] + bt[c + 1];
    const float o2 = (v[j].z - mean) * rs * g[c + 2] + bt[c + 2];
    const float o3 = (v[j].w - mean) * rs * g[c + 3] + bt[c + 3];
    if constexpr (OUTBF) {
      union { bf16 h[4]; uint2 u; } t;
      t.h[0] = f2bf(o0); t.h[1] = f2bf(o1); t.h[2] = f2bf(o2); t.h[3] = f2bf(o3);
      ((uint2*)(ob + (size_t)row * DIM))[tid + j * 256] = t.u;
    } else {
      float4 w4 = {o0, o1, o2, o3};
      ((float4*)(of + (size_t)row * DIM))[tid + j * 256] = w4;
    }
  }
}

// ---------------- RoPE ------------------------------------------------------
__global__ __launch_bounds__(256) void rope_tables(float* __restrict__ cT,
                                                   float* __restrict__ sT) {
  const int idx = blockIdx.x * 256 + threadIdx.x;
  if (idx >= NT * NHD) return;
  const int t = idx >> 7, d = idx & 127;
  const float inv = powf(10000.f, -(float)(d & 63) / 64.f);
  const float f = (float)t * inv;
  cT[idx] = cosf(f);
  sT[idx] = sinf(f);
}

__global__ __launch_bounds__(256) void rope_apply(bf16* __restrict__ q, bf16* __restrict__ k,
                                                  const float* __restrict__ cT,
                                                  const float* __restrict__ sT) {
  const int idx = blockIdx.x * 256 + threadIdx.x;  // pair index
  const int i = idx & 63;
  const int hh = (idx >> 6) & 7;
  const int row = idx >> 9;       // b*T + t
  const int t = row & (NT - 1);
  const size_t off = (size_t)row * NHID + hh * NHD + i * 2;
  const float c0 = cT[t * NHD + 2 * i], c1 = cT[t * NHD + 2 * i + 1];
  const float s0 = sT[t * NHD + 2 * i], s1 = sT[t * NHD + 2 * i + 1];
  union P2 { unsigned u; bf16 h[2]; };
  P2 a, o;
  a.u = *(const unsigned*)(q + off);
  float x0 = bf2f(a.h[0]), x1 = bf2f(a.h[1]);
  o.h[0] = f2bf(x0 * c0 - x1 * s0);
  o.h[1] = f2bf(x1 * c1 + x0 * s1);
  *(unsigned*)(q + off) = o.u;
  a.u = *(const unsigned*)(k + off);
  x0 = bf2f(a.h[0]); x1 = bf2f(a.h[1]);
  o.h[0] = f2bf(x0 * c0 - x1 * s0);
  o.h[1] = f2bf(x1 * c1 + x0 * s1);
  *(unsigned*)(k + off) = o.u;
}

// ---------------- Attention: per (b,h,16-row q tile) ------------------------
__global__ __launch_bounds__(256) void attn_kernel(
    const bf16* __restrict__ qb, const bf16* __restrict__ ksb,
    const bf16* __restrict__ vsb, const bf16* __restrict__ kab,
    const bf16* __restrict__ vab, const bf16* __restrict__ ktb,
    const bf16* __restrict__ vtb, const float* __restrict__ gate, int layer,
    bf16* __restrict__ out) {
  __shared__ float qs[16][132];
  __shared__ float kvs[66][132];
  __shared__ float ss[16][324];
  const int tid = threadIdx.x;
  const int bid = blockIdx.x;
  const int tt = (bid & 15) * 16;
  const int h = (bid >> 4) & 7;
  const int b = bid >> 7;
  const float gv = tanhf(gate[layer]);
  const float scale = 0.08838834764831845f;  // 1/sqrt(128)
  const int r = tid >> 4, l15 = tid & 15;

  {  // Q tile -> LDS (f32)
    const bf16* src = qb + ((size_t)(b * NT + tt + r) * NHID + h * NHD + l15 * 8);
    union { uint4 u; bf16 hh[8]; } t;
    t.u = *(const uint4*)src;
#pragma unroll
    for (int i2 = 0; i2 < 8; ++i2) qs[r][l15 * 8 + i2] = bf2f(t.hh[i2]);
  }

  // ---- scores ----
  for (int ci = 0; ci < 5; ++ci) {
    const int c0 = ci * 64, len = (ci == 4) ? 66 : 64;
    __syncthreads();
    for (int e = tid; e < len * 16; e += 256) {
      const int kr = e >> 4, d0 = (e & 15) * 8;
      const int gk = c0 + kr;
      const bf16* src;
      if (gk < 256)        src = ksb + ((size_t)(b * NT + gk) * NHID + h * NHD + d0);
      else if (gk < 258)   src = kab + ((size_t)(b * 2 + (gk - 256)) * NHID + h * NHD + d0);
      else                 src = ktb + ((size_t)(b * NKT + (gk - 258)) * NHID + h * NHD + d0);
      union { uint4 u; bf16 hh[8]; } t;
      t.u = *(const uint4*)src;
#pragma unroll
      for (int i2 = 0; i2 < 8; ++i2) kvs[kr][d0 + i2] = bf2f(t.hh[i2]);
    }
    __syncthreads();
    for (int kk = l15; kk < len; kk += 16) {
      const float4* q4 = (const float4*)(&qs[r][0]);
      const float4* k4 = (const float4*)(&kvs[kk][0]);
      float4 a4 = {0.f, 0.f, 0.f, 0.f};
#pragma unroll
      for (int dq = 0; dq < 32; ++dq) {
        const float4 a = q4[dq], bb4 = k4[dq];
        a4.x += a.x * bb4.x; a4.y += a.y * bb4.y;
        a4.z += a.z * bb4.z; a4.w += a.w * bb4.w;
      }
      float s_ = (a4.x + a4.y) + (a4.z + a4.w);
      const int gk = c0 + kk;
      s_ *= scale;
      if (gk >= 258) s_ *= gv;
      ss[r][gk] = s_;
    }
  }

  // ---- softmax over 322 (16 lanes per row, wave-internal shuffles) ----
  float mx = -1e30f;
  for (int kk = l15; kk < NKEYS; kk += 16) mx = fmaxf(mx, ss[r][kk]);
#pragma unroll
  for (int o = 8; o; o >>= 1) mx = fmaxf(mx, __shfl_xor(mx, o));
  float sm = 0.f;
  for (int kk = l15; kk < NKEYS; kk += 16) {
    const float e_ = __expf(ss[r][kk] - mx);
    ss[r][kk] = e_;
    sm += e_;
  }
#pragma unroll
  for (int o = 8; o; o >>= 1) sm += __shfl_xor(sm, o);
  const float inv = 1.f / sm;
  for (int kk = l15; kk < NKEYS; kk += 16) ss[r][kk] *= inv;

  // ---- PV ----
  float4 a0 = {0.f, 0.f, 0.f, 0.f}, a1 = {0.f, 0.f, 0.f, 0.f};
  for (int ci = 0; ci < 5; ++ci) {
    const int c0 = ci * 64, len = (ci == 4) ? 66 : 64;
    __syncthreads();
    for (int e = tid; e < len * 16; e += 256) {
      const int kr = e >> 4, d0 = (e & 15) * 8;
      const int gk = c0 + kr;
      const bf16* src;
      if (gk < 256)        src = vsb + ((size_t)(b * NT + gk) * NHID + h * NHD + d0);
      else if (gk < 258)   src = vab + ((size_t)(b * 2 + (gk - 256)) * NHID + h * NHD + d0);
      else                 src = vtb + ((size_t)(b * NKT + (gk - 258)) * NHID + h * NHD + d0);
      union { uint4 u; bf16 hh[8]; } t;
      t.u = *(const uint4*)src;
#pragma unroll
      for (int i2 = 0; i2 < 8; ++i2) kvs[kr][d0 + i2] = bf2f(t.hh[i2]);
    }
    __syncthreads();
    for (int kk = 0; kk < len; ++kk) {
      const float pp = ss[r][c0 + kk];
      const float4* kv4 = (const float4*)(&kvs[kk][0]);
      const float4 v0 = kv4[l15], v1 = kv4[l15 + 16];
      a0.x += pp * v0.x; a0.y += pp * v0.y; a0.z += pp * v0.z; a0.w += pp * v0.w;
      a1.x += pp * v1.x; a1.y += pp * v1.y; a1.z += pp * v1.z; a1.w += pp * v1.w;
    }
  }
  bf16* op = out + ((size_t)(b * NT + tt + r) * NHID + h * NHD);
  union { bf16 h4[4]; uint2 u; } w0, w1;
  w0.h4[0] = f2bf(a0.x); w0.h4[1] = f2bf(a0.y); w0.h4[2] = f2bf(a0.z); w0.h4[3] = f2bf(a0.w);
  w1.h4[0] = f2bf(a1.x); w1.h4[1] = f2bf(a1.y); w1.h4[2] = f2bf(a1.z); w1.h4[3] = f2bf(a1.w);
  ((uint2*)op)[l15] = w0.u;        // d = 4*l15
  ((uint2*)op)[l15 + 16] = w1.u;   // d = 64 + 4*l15
}

// ---------------- Final 12-wide head ---------------------------------------
__global__ __launch_bounds__(256) void head_kernel(const float* __restrict__ lnf,
                                                   const float* __restrict__ W2,
                                                   const float* __restrict__ b2,
                                                   float* __restrict__ out) {
  __shared__ float4 xs[4096];  // [c4][row] transposed: 16 rows x 1024
  const int r0 = blockIdx.x * 16;
  const float4* src = (const float4*)(lnf + (size_t)r0 * NHID);
  for (int e = threadIdx.x; e < 4096; e += 256) {
    const int row = e >> 8, c4 = e & 255;
    xs[c4 * 16 + row] = src[e];
  }
  __syncthreads();
  if (threadIdx.x < 192) {
    const int rr = threadIdx.x / 12, n = threadIdx.x % 12;
    const float4* w4 = (const float4*)(W2 + (size_t)n * NHID);
    float s = b2[n];
    for (int k = 0; k < 256; ++k) {
      const float4 a = xs[k * 16 + rr], w = w4[k];
      s += a.x * w.x + a.y * w.y + a.z * w.z + a.w * w.w;
    }
    out[(size_t)(r0 + rr) * NOUT + n] = s;
  }
}

// ---------------- conversions ----------------------------------------------
__global__ __launch_bounds__(256) void cvt_f32_bf16(const float* __restrict__ in,
                                                    bf16* __restrict__ o, int n4) {
  const int i = blockIdx.x * 256 + threadIdx.x;
  if (i >= n4) return;
  const float4 v = ((const float4*)in)[i];
  union { bf16 h[4]; uint2 u; } t;
  t.h[0] = f2bf(v.x); t.h[1] = f2bf(v.y); t.h[2] = f2bf(v.z); t.h[3] = f2bf(v.w);
  ((uint2*)o)[i] = t.u;
}

__global__ __launch_bounds__(256) void cvt_ht(const float* __restrict__ ht, int layer,
                                              bf16* __restrict__ o) {
  const int i = blockIdx.x * 256 + threadIdx.x;  // n4 = NB*NKT*NHID/4
  if (i >= NB * NKT * NHID / 4) return;
  const int c4 = i & 255;
  const int s = (i >> 8) & 63;
  const int bb = i >> 14;
  const float4 v =
      ((const float4*)(ht + ((size_t)((bb * NLAYER + layer) * NKT + s)) * NHID))[c4];
  union { bf16 h[4]; uint2 u; } t;
  t.h[0] = f2bf(v.x); t.h[1] = f2bf(v.y); t.h[2] = f2bf(v.z); t.h[3] = f2bf(v.w);
  ((uint2*)o)[i] = t.u;
}

__global__ __launch_bounds__(256) void build_had(const float* __restrict__ ha,
                                                 const float* __restrict__ p, int layer,
                                                 bf16* __restrict__ o) {
  const int i = blockIdx.x * 256 + threadIdx.x;  // n4 = NB*2*NHID/4
  if (i >= NB * 2 * NHID / 4) return;
  const int c4 = i & 255;
  const int s = (i >> 8) & 1;
  const int bb = i >> 9;
  const float* base = s ? (p + (size_t)bb * NHID) : (ha + (size_t)(bb * NLAYER + layer) * NHID);
  const float4 v = ((const float4*)base)[c4];
  union { bf16 h[4]; uint2 u; } t;
  t.h[0] = f2bf(v.x); t.h[1] = f2bf(v.y); t.h[2] = f2bf(v.z); t.h[3] = f2bf(v.w);
  ((uint2*)o)[i] = t.u;
}

// ---------------- host ------------------------------------------------------
extern "C" void kernel_launch(void* const* d_in, const int* in_sizes, int n_in,
                              void* d_out, int out_size, void* d_ws, size_t ws_size,
                              hipStream_t stream) {
  const float* x = (const float*)d_in[0];
  const float* h_a = (const float*)d_in[1];
  const float* h_t = (const float*)d_in[2];
  const float* p = (const float*)d_in[3];
  const float* ln1g = (const float*)d_in[4];
  const float* ln1b = (const float*)d_in[5];
  const float* W1 = (const float*)d_in[6];
  const float* b1 = (const float*)d_in[7];
  const float* Wq = (const float*)d_in[8];
  const float* bq = (const float*)d_in[9];
  const float* Wks = (const float*)d_in[10];
  const float* bks = (const float*)d_in[11];
  const float* Wvs = (const float*)d_in[12];
  const float* bvs = (const float*)d_in[13];
  const float* Wka = (const float*)d_in[14];
  const float* bka = (const float*)d_in[15];
  const float* Wva = (const float*)d_in[16];
  const float* bva = (const float*)d_in[17];
  const float* Wkt = (const float*)d_in[18];
  const float* bkt = (const float*)d_in[19];
  const float* Wvt = (const float*)d_in[20];
  const float* bvt = (const float*)d_in[21];
  const float* Wo = (const float*)d_in[22];
  const float* bo = (const float*)d_in[23];
  const float* gate = (const float*)d_in[24];
  const float* flng = (const float*)d_in[25];
  const float* flnb = (const float*)d_in[26];
  const float* Wf = (const float*)d_in[27];
  const float* bff = (const float*)d_in[28];
  const float* ln2g = (const float*)d_in[29];
  const float* ln2b = (const float*)d_in[30];
  const float* W2 = (const float*)d_in[31];
  const float* b2 = (const float*)d_in[32];

  char* wsp = (char*)d_ws;
  size_t off = 0;
  auto alloc = [&](size_t bytes) -> void* {
    void* rp = wsp + off;
    off = (off + bytes + 255) & ~(size_t)255;
    return rp;
  };
  const size_t MT = (size_t)NB * NT;  // 16384 rows

  bf16* W1b = (bf16*)alloc((size_t)NHID * NIN * 2);
  bf16* Wqb = (bf16*)alloc((size_t)NLAYER * NHID * NHID * 2);
  bf16* Wksb = (bf16*)alloc((size_t)NLAYER * NHID * NHID * 2);
  bf16* Wvsb = (bf16*)alloc((size_t)NLAYER * NHID * NHID * 2);
  bf16* Wkab = (bf16*)alloc((size_t)NLAYER * NHID * NHID * 2);
  bf16* Wvab = (bf16*)alloc((size_t)NLAYER * NHID * NHID * 2);
  bf16* Wktb = (bf16*)alloc((size_t)NLAYER * NHID * NHID * 2);
  bf16* Wvtb = (bf16*)alloc((size_t)NLAYER * NHID * NHID * 2);
  bf16* Wob = (bf16*)alloc((size_t)NLAYER * NHID * NHID * 2);
  bf16* Wfb = (bf16*)alloc((size_t)NLAYER * NHID * NHID * 2);
  float* ropeC = (float*)alloc((size_t)NT * NHD * 4);
  float* ropeS = (float*)alloc((size_t)NT * NHD * 4);
  float* hF = (float*)alloc(MT * NHID * 4);
  bf16* hB = (bf16*)alloc(MT * NHID * 2);
  bf16* regA = (bf16*)alloc(MT * NIN * 2);  // h0bf, later q/ks/vs/attout
  float* oF = (float*)alloc(MT * NHID * 4); // Wo out, later LN2 f32 out
  bf16* lnB = (bf16*)alloc(MT * NHID * 2);
  bf16* htiB = (bf16*)alloc((size_t)NB * NKT * NHID * 2);
  bf16* ktB = (bf16*)alloc((size_t)NB * NKT * NHID * 2);
  bf16* vtB = (bf16*)alloc((size_t)NB * NKT * NHID * 2);
  bf16* hadB = (bf16*)alloc((size_t)NB * 2 * NHID * 2);
  bf16* kaB = (bf16*)alloc((size_t)NB * 2 * NHID * 2);
  bf16* vaB = (bf16*)alloc((size_t)NB * 2 * NHID * 2);
  if (off > ws_size) {
    fprintf(stderr, "kernel_launch: ws too small (need %zu, have %zu)\n", off, ws_size);
    return;
  }

  bf16* h0b = regA;
  bf16* qB = regA;
  bf16* ksB = regA + MT * NHID;
  bf16* vsB = regA + 2 * MT * NHID;
  bf16* atB = regA + 3 * MT * NHID;

  // weights -> bf16
  cvt_f32_bf16<<<(NHID * NIN / 4) / 256, 256, 0, stream>>>(W1, W1b, NHID * NIN / 4);
  const int wn4 = NLAYER * NHID * NHID / 4;
  cvt_f32_bf16<<<wn4 / 256, 256, 0, stream>>>(Wq, Wqb, wn4);
  cvt_f32_bf16<<<wn4 / 256, 256, 0, stream>>>(Wks, Wksb, wn4);
  cvt_f32_bf16<<<wn4 / 256, 256, 0, stream>>>(Wvs, Wvsb, wn4);
  cvt_f32_bf16<<<wn4 / 256, 256, 0, stream>>>(Wka, Wkab, wn4);
  cvt_f32_bf16<<<wn4 / 256, 256, 0, stream>>>(Wva, Wvab, wn4);
  cvt_f32_bf16<<<wn4 / 256, 256, 0, stream>>>(Wkt, Wktb, wn4);
  cvt_f32_bf16<<<wn4 / 256, 256, 0, stream>>>(Wvt, Wvtb, wn4);
  cvt_f32_bf16<<<wn4 / 256, 256, 0, stream>>>(Wo, Wob, wn4);
  cvt_f32_bf16<<<wn4 / 256, 256, 0, stream>>>(Wf, Wfb, wn4);
  rope_tables<<<(NT * NHD + 255) / 256, 256, 0, stream>>>(ropeC, ropeS);

  // stage 1: LN1 -> W1 (relu)
  ln_kernel<NIN, false, true><<<MT, 256, 0, stream>>>(x, nullptr, ln1g, ln1b, h0b, nullptr);
  gemm_bt<2, true><<<dim3(MT / 128, NHID / 128), 256, 0, stream>>>(
      h0b, W1b, b1, hF, hB, (int)MT, NHID, NIN);

  for (int li = 0; li < NLAYER; ++li) {
    const size_t wo_ = (size_t)li * NHID * NHID;
    build_had<<<(NB * 2 * NHID / 4) / 256, 256, 0, stream>>>(h_a, p, li, hadB);
    cvt_ht<<<(NB * NKT * NHID / 4) / 256, 256, 0, stream>>>(h_t, li, htiB);
    gemm_bt<1, false><<<dim3(MT / 128, 8), 256, 0, stream>>>(
        hB, Wqb + wo_, bq + li * NHID, nullptr, qB, (int)MT, NHID, NHID);
    gemm_bt<1, false><<<dim3(MT / 128, 8), 256, 0, stream>>>(
        hB, Wksb + wo_, bks + li * NHID, nullptr, ksB, (int)MT, NHID, NHID);
    gemm_bt<1, false><<<dim3(MT / 128, 8), 256, 0, stream>>>(
        hB, Wvsb + wo_, bvs + li * NHID, nullptr, vsB, (int)MT, NHID, NHID);
    gemm_bt<1, false><<<dim3(1, 8), 256, 0, stream>>>(
        hadB, Wkab + wo_, bka + li * NHID, nullptr, kaB, NB * 2, NHID, NHID);
    gemm_bt<1, false><<<dim3(1, 8), 256, 0, stream>>>(
        hadB, Wvab + wo_, bva + li * NHID, nullptr, vaB, NB * 2, NHID, NHID);
    gemm_bt<1, false><<<dim3(NB * NKT / 128, 8), 256, 0, stream>>>(
        htiB, Wktb + wo_, bkt + li * NHID, nullptr, ktB, NB * NKT, NHID, NHID);
    gemm_bt<1, false><<<dim3(NB * NKT / 128, 8), 256, 0, stream>>>(
        htiB, Wvtb + wo_, bvt + li * NHID, nullptr, vtB, NB * NKT, NHID, NHID);
    rope_apply<<<(int)(MT * NHID / 2 / 256), 256, 0, stream>>>(qB, ksB, ropeC, ropeS);
    attn_kernel<<<NB * NHEAD * (NT / 16), 256, 0, stream>>>(
        qB, ksB, vsB, kaB, vaB, ktB, vtB, gate, li, atB);
    gemm_bt<0, false><<<dim3(MT / 128, 8), 256, 0, stream>>>(
        atB, Wob + wo_, bo + li * NHID, oF, nullptr, (int)MT, NHID, NHID);
    ln_kernel<NHID, true, true><<<MT, 256, 0, stream>>>(
        oF, hF, flng + li * NHID, flnb + li * NHID, lnB, nullptr);
    gemm_bt<2, true><<<dim3(MT / 128, 8), 256, 0, stream>>>(
        lnB, Wfb + wo_, bff + li * NHID, hF, hB, (int)MT, NHID, NHID);
  }

  // final LN (f32 out for precision) + 12-wide head
  ln_kernel<NHID, false, false><<<MT, 256, 0, stream>>>(hF, nullptr, ln2g, ln2b, nullptr, oF);
  head_kernel<<<MT / 16, 256, 0, stream>>>(oF, W2, b2, (float*)d_out);
}

// Round 6
// 2226.365 us; speedup vs baseline: 11.5228x; 11.5228x over previous
//
#include <hip/hip_runtime.h>
#include <hip/hip_bf16.h>
#include <cstdio>

typedef __hip_bfloat16 bf16;
typedef __attribute__((ext_vector_type(8))) short bf16x8;
typedef __attribute__((ext_vector_type(4))) float f32x4;

constexpr int NB = 64, NT = 256, NIN = 4096, NHID = 1024, NHEAD = 8, NHD = 128;
constexpr int NLAYER = 2, NKT = 64, NKEYS = 322, NOUT = 12;

__device__ __forceinline__ float bf2f(bf16 v) { return __bfloat162float(v); }
__device__ __forceinline__ bf16 f2bf(float v) { return __float2bfloat16(v); }

__device__ __forceinline__ void gload16(const void* g, void* l) {
  __builtin_amdgcn_global_load_lds((const __attribute__((address_space(1))) void*)g,
                                   (__attribute__((address_space(3))) void*)l, 16, 0, 0);
}

// ---------------- GEMM: C[M,N] = A[M,K] @ W[N,K]^T + bias, optional relu ----
// OMODE: 0 = f32 out, 1 = bf16 out, 2 = both.  M%128==0, N%128==0, K%32==0.
template <int OMODE, bool RELU>
__global__ __launch_bounds__(256) void gemm_bt(
    const bf16* __restrict__ A, const bf16* __restrict__ W,
    const float* __restrict__ bias, float* __restrict__ Cf,
    bf16* __restrict__ Cb, int M, int N, int K) {
  __shared__ bf16 As[128 * 32];
  __shared__ bf16 Bs[128 * 32];
  const int tid = threadIdx.x;
  const int wave = tid >> 6, lane = tid & 63;
  const int m0 = blockIdx.x * 128, n0 = blockIdx.y * 128;
  const int wm = (wave >> 1) * 64, wn = (wave & 1) * 64;
  const int lr = lane >> 4, lc = lane & 15;

  f32x4 acc[4][4];
#pragma unroll
  for (int i = 0; i < 4; ++i)
#pragma unroll
    for (int j = 0; j < 4; ++j) acc[i][j] = (f32x4){0.f, 0.f, 0.f, 0.f};

  for (int k0 = 0; k0 < K; k0 += 32) {
#pragma unroll
    for (int j = 0; j < 2; ++j) {
      const int c = (wave * 2 + j) * 64 + lane;     // chunk 0..511
      const int row = c >> 2, kq = (c & 3) * 8;     // 4 chunks/row of 64B
      gload16(A + (size_t)(m0 + row) * K + k0 + kq, (char*)As + (size_t)(wave * 2 + j) * 1024);
      gload16(W + (size_t)(n0 + row) * K + k0 + kq, (char*)Bs + (size_t)(wave * 2 + j) * 1024);
    }
    __syncthreads();  // drains global_load_lds (vmcnt0 before barrier)
    bf16x8 af[4], bv[4];
#pragma unroll
    for (int mi = 0; mi < 4; ++mi)
      af[mi] = *(const bf16x8*)(As + (wm + mi * 16 + lc) * 32 + lr * 8);
#pragma unroll
    for (int ni = 0; ni < 4; ++ni)
      bv[ni] = *(const bf16x8*)(Bs + (wn + ni * 16 + lc) * 32 + lr * 8);
#pragma unroll
    for (int mi = 0; mi < 4; ++mi)
#pragma unroll
      for (int ni = 0; ni < 4; ++ni)
        acc[mi][ni] = __builtin_amdgcn_mfma_f32_16x16x32_bf16(af[mi], bv[ni], acc[mi][ni], 0, 0, 0);
    __syncthreads();
  }

#pragma unroll
  for (int mi = 0; mi < 4; ++mi)
#pragma unroll
    for (int ni = 0; ni < 4; ++ni) {
      const int col = n0 + wn + ni * 16 + lc;
      const float bb = bias[col];
#pragma unroll
      for (int i = 0; i < 4; ++i) {
        const int row = m0 + wm + mi * 16 + lr * 4 + i;
        float v = acc[mi][ni][i] + bb;
        if (RELU) v = fmaxf(v, 0.f);
        if constexpr (OMODE == 0 || OMODE == 2) Cf[(size_t)row * N + col] = v;
        if constexpr (OMODE == 1 || OMODE == 2) Cb[(size_t)row * N + col] = f2bf(v);
      }
    }
}

// ---------------- LayerNorm (one block per row) -----------------------------
template <int DIM, bool RES, bool OUTBF>
__global__ __launch_bounds__(256) void ln_kernel(
    const float* __restrict__ X, const float* __restrict__ R,
    const float* __restrict__ g, const float* __restrict__ bt,
    bf16* __restrict__ ob, float* __restrict__ of) {
  constexpr int PT = DIM / 1024;  // float4s per thread
  const int row = blockIdx.x, tid = threadIdx.x;
  const float4* xr = (const float4*)(X + (size_t)row * DIM);
  float4 v[PT];
  float s = 0.f, sq = 0.f;
#pragma unroll
  for (int j = 0; j < PT; ++j) {
    v[j] = xr[tid + j * 256];
    if constexpr (RES) {
      const float4 r4 = ((const float4*)(R + (size_t)row * DIM))[tid + j * 256];
      v[j].x += r4.x; v[j].y += r4.y; v[j].z += r4.z; v[j].w += r4.w;
    }
    s += v[j].x + v[j].y + v[j].z + v[j].w;
    sq += v[j].x * v[j].x + v[j].y * v[j].y + v[j].z * v[j].z + v[j].w * v[j].w;
  }
#pragma unroll
  for (int o = 32; o; o >>= 1) { s += __shfl_down(s, o); sq += __shfl_down(sq, o); }
  __shared__ float red[8];
  const int wave = tid >> 6, lane = tid & 63;
  if (!lane) { red[wave] = s; red[wave + 4] = sq; }
  __syncthreads();
  s = red[0] + red[1] + red[2] + red[3];
  sq = red[4] + red[5] + red[6] + red[7];
  const float mean = s * (1.f / DIM);
  const float var = sq * (1.f / DIM) - mean * mean;
  const float rs = rsqrtf(var + 1e-5f);
#pragma unroll
  for (int j = 0; j < PT; ++j) {
    const int c = (tid + j * 256) * 4;
    const float o0 = (v[j].x - mean) * rs * g[c + 0] + bt[c + 0];
    const float o1 = (v[j].y - mean) * rs * g[c + 1] + bt[c + 1];
    const float o2 = (v[j].z - mean) * rs * g[c + 2] + bt[c + 2];
    const float o3 = (v[j].w - mean) * rs * g[c + 3] + bt[c + 3];
    if constexpr (OUTBF) {
      union { bf16 h[4]; uint2 u; } t;
      t.h[0] = f2bf(o0); t.h[1] = f2bf(o1); t.h[2] = f2bf(o2); t.h[3] = f2bf(o3);
      ((uint2*)(ob + (size_t)row * DIM))[tid + j * 256] = t.u;
    } else {
      float4 w4 = {o0, o1, o2, o3};
      ((float4*)(of + (size_t)row * DIM))[tid + j * 256] = w4;
    }
  }
}

// ---------------- RoPE ------------------------------------------------------
__global__ __launch_bounds__(256) void rope_tables(float* __restrict__ cT,
                                                   float* __restrict__ sT) {
  const int idx = blockIdx.x * 256 + threadIdx.x;
  if (idx >= NT * NHD) return;
  const int t = idx >> 7, d = idx & 127;
  const float inv = powf(10000.f, -(float)(d & 63) / 64.f);
  const float f = (float)t * inv;
  cT[idx] = cosf(f);
  sT[idx] = sinf(f);
}

__global__ __launch_bounds__(256) void rope_apply(bf16* __restrict__ q, bf16* __restrict__ k,
                                                  const float* __restrict__ cT,
                                                  const float* __restrict__ sT) {
  const int idx = blockIdx.x * 256 + threadIdx.x;  // pair index
  const int i = idx & 63;
  const int hh = (idx >> 6) & 7;
  const int row = idx >> 9;       // b*T + t
  const int t = row & (NT - 1);
  const size_t off = (size_t)row * NHID + hh * NHD + i * 2;
  const float c0 = cT[t * NHD + 2 * i], c1 = cT[t * NHD + 2 * i + 1];
  const float s0 = sT[t * NHD + 2 * i], s1 = sT[t * NHD + 2 * i + 1];
  union P2 { unsigned u; bf16 h[2]; };
  P2 a, o;
  a.u = *(const unsigned*)(q + off);
  float x0 = bf2f(a.h[0]), x1 = bf2f(a.h[1]);
  o.h[0] = f2bf(x0 * c0 - x1 * s0);
  o.h[1] = f2bf(x1 * c1 + x0 * s1);
  *(unsigned*)(q + off) = o.u;
  a.u = *(const unsigned*)(k + off);
  x0 = bf2f(a.h[0]); x1 = bf2f(a.h[1]);
  o.h[0] = f2bf(x0 * c0 - x1 * s0);
  o.h[1] = f2bf(x1 * c1 + x0 * s1);
  *(unsigned*)(k + off) = o.u;
}

// ---------------- MFMA flash attention --------------------------------------
// Block = (b, h, 64-row q chunk); 4 waves x 16 q rows. KV tiles of 64 keys,
// 6 tiles (322 keys padded to 384, pad masked to -inf). K in LDS [64][128]
// bf16 XOR-swizzled; V transposed in LDS [128][64] bf16 XOR-swizzled; P
// redistributed C-layout -> A-layout via small padded per-wave LDS buffer.
__global__ __launch_bounds__(256) void attn_mfma(
    const bf16* __restrict__ qb, const bf16* __restrict__ ksb,
    const bf16* __restrict__ vsb, const bf16* __restrict__ kab,
    const bf16* __restrict__ vab, const bf16* __restrict__ ktb,
    const bf16* __restrict__ vtb, const float* __restrict__ gate, int layer,
    bf16* __restrict__ out) {
  __shared__ char Ks[64 * 256];    // K tile, row=key (256B), swizzled
  __shared__ char Vts[128 * 128];  // V^T tile, row=d (128B), swizzled
  __shared__ bf16 Pl[4][16][72];   // per-wave P tile, row=q, padded to 144B
  const int tid = threadIdx.x;
  const int w = tid >> 6, lane = tid & 63;
  const int lr = lane >> 4, lc = lane & 15;
  const int bid = blockIdx.x;
  const int qc = bid & 3, h = (bid >> 2) & 7, b = bid >> 5;
  const int q0 = qc * 64 + w * 16;
  const float gv = tanhf(gate[layer]);
  const float scale = 0.08838834764831845f;  // 1/sqrt(128)

  // Q fragments (16 rows x 128 d), A-layout: row=lc, k-chunk=lr*8
  bf16x8 af[4];
#pragma unroll
  for (int ks_ = 0; ks_ < 4; ++ks_)
    af[ks_] = *(const bf16x8*)(qb + (size_t)(b * NT + q0 + lc) * NHID + h * NHD +
                               ks_ * 32 + lr * 8);

  f32x4 o[8];
#pragma unroll
  for (int n2 = 0; n2 < 8; ++n2) o[n2] = (f32x4){0.f, 0.f, 0.f, 0.f};
  float m_[4] = {-1e30f, -1e30f, -1e30f, -1e30f};
  float l_[4] = {0.f, 0.f, 0.f, 0.f};

  for (int kb = 0; kb < 6; ++kb) {
    // ---- cooperative stage: K -> Ks (swizzled), V -> Vts (transposed+swz) --
#pragma unroll
    for (int i = 0; i < 4; ++i) {
      const int c = tid + i * 256;
      const int key = c >> 4, d0 = (c & 15) * 8;
      const int gk = kb * 64 + key;
      const bf16 *ksrc, *vsrc;
      if (gk < 256) {
        const size_t r = (size_t)(b * NT + gk) * NHID;
        ksrc = ksb + r; vsrc = vsb + r;
      } else if (gk < 258) {
        const size_t r = (size_t)(b * 2 + (gk - 256)) * NHID;
        ksrc = kab + r; vsrc = vab + r;
      } else if (gk < NKEYS) {
        const size_t r = (size_t)(b * NKT + (gk - 258)) * NHID;
        ksrc = ktb + r; vsrc = vtb + r;
      } else {  // pad: any finite data, scores masked below
        const size_t r = (size_t)(b * NT) * NHID;
        ksrc = ksb + r; vsrc = vsb + r;
      }
      const uint4 kv_ = *(const uint4*)(ksrc + h * NHD + d0);
      const uint4 vv_ = *(const uint4*)(vsrc + h * NHD + d0);
      *(uint4*)(Ks + key * 256 + ((d0 * 2) ^ ((key & 7) << 4))) = kv_;
      union { uint4 u; bf16 hh[8]; } t;
      t.u = vv_;
#pragma unroll
      for (int j = 0; j < 8; ++j) {
        const int d = d0 + j;
        *(bf16*)(Vts + d * 128 + ((key * 2) ^ ((d & 7) << 4))) = t.hh[j];
      }
    }
    __syncthreads();

    // ---- S = Q K^T for this tile: 4 key sub-tiles x 4 k-steps --------------
    f32x4 s_[4];
#pragma unroll
    for (int n = 0; n < 4; ++n) s_[n] = (f32x4){0.f, 0.f, 0.f, 0.f};
#pragma unroll
    for (int n = 0; n < 4; ++n) {
      const int row = n * 16 + lc;
#pragma unroll
      for (int ks_ = 0; ks_ < 4; ++ks_) {
        const bf16x8 bk =
            *(const bf16x8*)(Ks + row * 256 + ((ks_ * 64 + lr * 16) ^ ((row & 7) << 4)));
        s_[n] = __builtin_amdgcn_mfma_f32_16x16x32_bf16(af[ks_], bk, s_[n], 0, 0, 0);
      }
    }
    // scale + gate + pad mask (col = lc per C-layout)
#pragma unroll
    for (int n = 0; n < 4; ++n) {
      const int gk = kb * 64 + n * 16 + lc;
      const float f = scale * (gk >= 258 ? gv : 1.f);
#pragma unroll
      for (int i = 0; i < 4; ++i)
        s_[n][i] = (gk >= NKEYS) ? -1e30f : s_[n][i] * f;
    }

    // ---- online softmax: row r = lr*4+i, 16-lane butterfly over cols -------
    float corr[4];
#pragma unroll
    for (int i = 0; i < 4; ++i) {
      float mx = fmaxf(fmaxf(s_[0][i], s_[1][i]), fmaxf(s_[2][i], s_[3][i]));
#pragma unroll
      for (int off = 8; off; off >>= 1) mx = fmaxf(mx, __shfl_xor(mx, off));
      const float mnew = fmaxf(m_[i], mx);
      corr[i] = __expf(m_[i] - mnew);
      m_[i] = mnew;
      float rs = 0.f;
#pragma unroll
      for (int n = 0; n < 4; ++n) {
        const float p = __expf(s_[n][i] - mnew);
        s_[n][i] = p;
        rs += p;
      }
#pragma unroll
      for (int off = 8; off; off >>= 1) rs += __shfl_xor(rs, off);
      l_[i] = l_[i] * corr[i] + rs;
#pragma unroll
      for (int n = 0; n < 4; ++n) Pl[w][lr * 4 + i][n * 16 + lc] = f2bf(s_[n][i]);
    }
#pragma unroll
    for (int n2 = 0; n2 < 8; ++n2)
#pragma unroll
      for (int i = 0; i < 4; ++i) o[n2][i] *= corr[i];

    // wave-local ds_write -> ds_read ordering for Pl
    asm volatile("s_waitcnt lgkmcnt(0)" ::: "memory");

    // ---- O += P V : A = P[16q x 64k], B = V^T[d][k] ------------------------
    const bf16x8 pa0 = *(const bf16x8*)(&Pl[w][lc][lr * 8]);
    const bf16x8 pa1 = *(const bf16x8*)(&Pl[w][lc][32 + lr * 8]);
#pragma unroll
    for (int n2 = 0; n2 < 8; ++n2) {
      const int row = n2 * 16 + lc;
      const bf16x8 bv0 =
          *(const bf16x8*)(Vts + row * 128 + ((lr * 16) ^ ((row & 7) << 4)));
      const bf16x8 bv1 =
          *(const bf16x8*)(Vts + row * 128 + ((64 + lr * 16) ^ ((row & 7) << 4)));
      o[n2] = __builtin_amdgcn_mfma_f32_16x16x32_bf16(pa0, bv0, o[n2], 0, 0, 0);
      o[n2] = __builtin_amdgcn_mfma_f32_16x16x32_bf16(pa1, bv1, o[n2], 0, 0, 0);
    }
    __syncthreads();
  }

  // ---- epilogue: O /= l, write bf16 ----------------------------------------
#pragma unroll
  for (int i = 0; i < 4; ++i) {
    const float inv = 1.f / l_[i];
    bf16* op = out + (size_t)(b * NT + q0 + lr * 4 + i) * NHID + h * NHD;
#pragma unroll
    for (int n2 = 0; n2 < 8; ++n2) op[n2 * 16 + lc] = f2bf(o[n2][i] * inv);
  }
}

// ---------------- Final 12-wide head ---------------------------------------
__global__ __launch_bounds__(256) void head_kernel(const float* __restrict__ lnf,
                                                   const float* __restrict__ W2,
                                                   const float* __restrict__ b2,
                                                   float* __restrict__ out) {
  __shared__ float4 xs[4096];  // [c4][row] transposed: 16 rows x 1024
  const int r0 = blockIdx.x * 16;
  const float4* src = (const float4*)(lnf + (size_t)r0 * NHID);
  for (int e = threadIdx.x; e < 4096; e += 256) {
    const int row = e >> 8, c4 = e & 255;
    xs[c4 * 16 + row] = src[e];
  }
  __syncthreads();
  if (threadIdx.x < 192) {
    const int rr = threadIdx.x / 12, n = threadIdx.x % 12;
    const float4* w4 = (const float4*)(W2 + (size_t)n * NHID);
    float s = b2[n];
    for (int k = 0; k < 256; ++k) {
      const float4 a = xs[k * 16 + rr], w = w4[k];
      s += a.x * w.x + a.y * w.y + a.z * w.z + a.w * w.w;
    }
    out[(size_t)(r0 + rr) * NOUT + n] = s;
  }
}

// ---------------- conversions ----------------------------------------------
__global__ __launch_bounds__(256) void cvt_f32_bf16(const float* __restrict__ in,
                                                    bf16* __restrict__ o, int n4) {
  const int i = blockIdx.x * 256 + threadIdx.x;
  if (i >= n4) return;
  const float4 v = ((const float4*)in)[i];
  union { bf16 h[4]; uint2 u; } t;
  t.h[0] = f2bf(v.x); t.h[1] = f2bf(v.y); t.h[2] = f2bf(v.z); t.h[3] = f2bf(v.w);
  ((uint2*)o)[i] = t.u;
}

__global__ __launch_bounds__(256) void cvt_ht(const float* __restrict__ ht, int layer,
                                              bf16* __restrict__ o) {
  const int i = blockIdx.x * 256 + threadIdx.x;  // n4 = NB*NKT*NHID/4
  if (i >= NB * NKT * NHID / 4) return;
  const int c4 = i & 255;
  const int s = (i >> 8) & 63;
  const int bb = i >> 14;
  const float4 v =
      ((const float4*)(ht + ((size_t)((bb * NLAYER + layer) * NKT + s)) * NHID))[c4];
  union { bf16 h[4]; uint2 u; } t;
  t.h[0] = f2bf(v.x); t.h[1] = f2bf(v.y); t.h[2] = f2bf(v.z); t.h[3] = f2bf(v.w);
  ((uint2*)o)[i] = t.u;
}

__global__ __launch_bounds__(256) void build_had(const float* __restrict__ ha,
                                                 const float* __restrict__ p, int layer,
                                                 bf16* __restrict__ o) {
  const int i = blockIdx.x * 256 + threadIdx.x;  // n4 = NB*2*NHID/4
  if (i >= NB * 2 * NHID / 4) return;
  const int c4 = i & 255;
  const int s = (i >> 8) & 1;
  const int bb = i >> 9;
  const float* base = s ? (p + (size_t)bb * NHID) : (ha + (size_t)(bb * NLAYER + layer) * NHID);
  const float4 v = ((const float4*)base)[c4];
  union { bf16 h[4]; uint2 u; } t;
  t.h[0] = f2bf(v.x); t.h[1] = f2bf(v.y); t.h[2] = f2bf(v.z); t.h[3] = f2bf(v.w);
  ((uint2*)o)[i] = t.u;
}

// ---------------- host ------------------------------------------------------
extern "C" void kernel_launch(void* const* d_in, const int* in_sizes, int n_in,
                              void* d_out, int out_size, void* d_ws, size_t ws_size,
                              hipStream_t stream) {
  const float* x = (const float*)d_in[0];
  const float* h_a = (const float*)d_in[1];
  const float* h_t = (const float*)d_in[2];
  const float* p = (const float*)d_in[3];
  const float* ln1g = (const float*)d_in[4];
  const float* ln1b = (const float*)d_in[5];
  const float* W1 = (const float*)d_in[6];
  const float* b1 = (const float*)d_in[7];
  const float* Wq = (const float*)d_in[8];
  const float* bq = (const float*)d_in[9];
  const float* Wks = (const float*)d_in[10];
  const float* bks = (const float*)d_in[11];
  const float* Wvs = (const float*)d_in[12];
  const float* bvs = (const float*)d_in[13];
  const float* Wka = (const float*)d_in[14];
  const float* bka = (const float*)d_in[15];
  const float* Wva = (const float*)d_in[16];
  const float* bva = (const float*)d_in[17];
  const float* Wkt = (const float*)d_in[18];
  const float* bkt = (const float*)d_in[19];
  const float* Wvt = (const float*)d_in[20];
  const float* bvt = (const float*)d_in[21];
  const float* Wo = (const float*)d_in[22];
  const float* bo = (const float*)d_in[23];
  const float* gate = (const float*)d_in[24];
  const float* flng = (const float*)d_in[25];
  const float* flnb = (const float*)d_in[26];
  const float* Wf = (const float*)d_in[27];
  const float* bff = (const float*)d_in[28];
  const float* ln2g = (const float*)d_in[29];
  const float* ln2b = (const float*)d_in[30];
  const float* W2 = (const float*)d_in[31];
  const float* b2 = (const float*)d_in[32];

  char* wsp = (char*)d_ws;
  size_t off = 0;
  auto alloc = [&](size_t bytes) -> void* {
    void* rp = wsp + off;
    off = (off + bytes + 255) & ~(size_t)255;
    return rp;
  };
  const size_t MT = (size_t)NB * NT;  // 16384 rows

  bf16* W1b = (bf16*)alloc((size_t)NHID * NIN * 2);
  bf16* Wqb = (bf16*)alloc((size_t)NLAYER * NHID * NHID * 2);
  bf16* Wksb = (bf16*)alloc((size_t)NLAYER * NHID * NHID * 2);
  bf16* Wvsb = (bf16*)alloc((size_t)NLAYER * NHID * NHID * 2);
  bf16* Wkab = (bf16*)alloc((size_t)NLAYER * NHID * NHID * 2);
  bf16* Wvab = (bf16*)alloc((size_t)NLAYER * NHID * NHID * 2);
  bf16* Wktb = (bf16*)alloc((size_t)NLAYER * NHID * NHID * 2);
  bf16* Wvtb = (bf16*)alloc((size_t)NLAYER * NHID * NHID * 2);
  bf16* Wob = (bf16*)alloc((size_t)NLAYER * NHID * NHID * 2);
  bf16* Wfb = (bf16*)alloc((size_t)NLAYER * NHID * NHID * 2);
  float* ropeC = (float*)alloc((size_t)NT * NHD * 4);
  float* ropeS = (float*)alloc((size_t)NT * NHD * 4);
  float* hF = (float*)alloc(MT * NHID * 4);
  bf16* hB = (bf16*)alloc(MT * NHID * 2);
  bf16* regA = (bf16*)alloc(MT * NIN * 2);  // h0bf, later q/ks/vs/attout
  float* oF = (float*)alloc(MT * NHID * 4); // Wo out, later LN2 f32 out
  bf16* lnB = (bf16*)alloc(MT * NHID * 2);
  bf16* htiB = (bf16*)alloc((size_t)NB * NKT * NHID * 2);
  bf16* ktB = (bf16*)alloc((size_t)NB * NKT * NHID * 2);
  bf16* vtB = (bf16*)alloc((size_t)NB * NKT * NHID * 2);
  bf16* hadB = (bf16*)alloc((size_t)NB * 2 * NHID * 2);
  bf16* kaB = (bf16*)alloc((size_t)NB * 2 * NHID * 2);
  bf16* vaB = (bf16*)alloc((size_t)NB * 2 * NHID * 2);
  if (off > ws_size) {
    fprintf(stderr, "kernel_launch: ws too small (need %zu, have %zu)\n", off, ws_size);
    return;
  }

  bf16* h0b = regA;
  bf16* qB = regA;
  bf16* ksB = regA + MT * NHID;
  bf16* vsB = regA + 2 * MT * NHID;
  bf16* atB = regA + 3 * MT * NHID;

  // weights -> bf16
  cvt_f32_bf16<<<(NHID * NIN / 4) / 256, 256, 0, stream>>>(W1, W1b, NHID * NIN / 4);
  const int wn4 = NLAYER * NHID * NHID / 4;
  cvt_f32_bf16<<<wn4 / 256, 256, 0, stream>>>(Wq, Wqb, wn4);
  cvt_f32_bf16<<<wn4 / 256, 256, 0, stream>>>(Wks, Wksb, wn4);
  cvt_f32_bf16<<<wn4 / 256, 256, 0, stream>>>(Wvs, Wvsb, wn4);
  cvt_f32_bf16<<<wn4 / 256, 256, 0, stream>>>(Wka, Wkab, wn4);
  cvt_f32_bf16<<<wn4 / 256, 256, 0, stream>>>(Wva, Wvab, wn4);
  cvt_f32_bf16<<<wn4 / 256, 256, 0, stream>>>(Wkt, Wktb, wn4);
  cvt_f32_bf16<<<wn4 / 256, 256, 0, stream>>>(Wvt, Wvtb, wn4);
  cvt_f32_bf16<<<wn4 / 256, 256, 0, stream>>>(Wo, Wob, wn4);
  cvt_f32_bf16<<<wn4 / 256, 256, 0, stream>>>(Wf, Wfb, wn4);
  rope_tables<<<(NT * NHD + 255) / 256, 256, 0, stream>>>(ropeC, ropeS);

  // stage 1: LN1 -> W1 (relu)
  ln_kernel<NIN, false, true><<<MT, 256, 0, stream>>>(x, nullptr, ln1g, ln1b, h0b, nullptr);
  gemm_bt<2, true><<<dim3(MT / 128, NHID / 128), 256, 0, stream>>>(
      h0b, W1b, b1, hF, hB, (int)MT, NHID, NIN);

  for (int li = 0; li < NLAYER; ++li) {
    const size_t wo_ = (size_t)li * NHID * NHID;
    build_had<<<(NB * 2 * NHID / 4) / 256, 256, 0, stream>>>(h_a, p, li, hadB);
    cvt_ht<<<(NB * NKT * NHID / 4) / 256, 256, 0, stream>>>(h_t, li, htiB);
    gemm_bt<1, false><<<dim3(MT / 128, 8), 256, 0, stream>>>(
        hB, Wqb + wo_, bq + li * NHID, nullptr, qB, (int)MT, NHID, NHID);
    gemm_bt<1, false><<<dim3(MT / 128, 8), 256, 0, stream>>>(
        hB, Wksb + wo_, bks + li * NHID, nullptr, ksB, (int)MT, NHID, NHID);
    gemm_bt<1, false><<<dim3(MT / 128, 8), 256, 0, stream>>>(
        hB, Wvsb + wo_, bvs + li * NHID, nullptr, vsB, (int)MT, NHID, NHID);
    gemm_bt<1, false><<<dim3(1, 8), 256, 0, stream>>>(
        hadB, Wkab + wo_, bka + li * NHID, nullptr, kaB, NB * 2, NHID, NHID);
    gemm_bt<1, false><<<dim3(1, 8), 256, 0, stream>>>(
        hadB, Wvab + wo_, bva + li * NHID, nullptr, vaB, NB * 2, NHID, NHID);
    gemm_bt<1, false><<<dim3(NB * NKT / 128, 8), 256, 0, stream>>>(
        htiB, Wktb + wo_, bkt + li * NHID, nullptr, ktB, NB * NKT, NHID, NHID);
    gemm_bt<1, false><<<dim3(NB * NKT / 128, 8), 256, 0, stream>>>(
        htiB, Wvtb + wo_, bvt + li * NHID, nullptr, vtB, NB * NKT, NHID, NHID);
    rope_apply<<<(int)(MT * NHID / 2 / 256), 256, 0, stream>>>(qB, ksB, ropeC, ropeS);
    attn_mfma<<<NB * NHEAD * 4, 256, 0, stream>>>(
        qB, ksB, vsB, kaB, vaB, ktB, vtB, gate, li, atB);
    gemm_bt<0, false><<<dim3(MT / 128, 8), 256, 0, stream>>>(
        atB, Wob + wo_, bo + li * NHID, oF, nullptr, (int)MT, NHID, NHID);
    ln_kernel<NHID, true, true><<<MT, 256, 0, stream>>>(
        oF, hF, flng + li * NHID, flnb + li * NHID, lnB, nullptr);
    gemm_bt<2, true><<<dim3(MT / 128, 8), 256, 0, stream>>>(
        lnB, Wfb + wo_, bff + li * NHID, hF, hB, (int)MT, NHID, NHID);
  }

  // final LN (f32 out for precision) + 12-wide head
  ln_kernel<NHID, false, false><<<MT, 256, 0, stream>>>(hF, nullptr, ln2g, ln2b, nullptr, oF);
  head_kernel<<<MT / 16, 256, 0, stream>>>(oF, W2, b2, (float*)d_out);
}

// Round 8
// 2049.500 us; speedup vs baseline: 12.5172x; 1.0863x over previous
//
#include <hip/hip_runtime.h>
#include <hip/hip_bf16.h>
#include <cstdio>

typedef __hip_bfloat16 bf16;
typedef __attribute__((ext_vector_type(8))) short bf16x8;
typedef __attribute__((ext_vector_type(4))) float f32x4;

constexpr int NB = 64, NT = 256, NIN = 4096, NHID = 1024, NHEAD = 8, NHD = 128;
constexpr int NLAYER = 2, NKT = 64, NKEYS = 322, NOUT = 12;

__device__ __forceinline__ float bf2f(bf16 v) { return __bfloat162float(v); }
__device__ __forceinline__ bf16 f2bf(float v) { return __float2bfloat16(v); }

__device__ __forceinline__ void gload16(const void* g, void* l) {
  __builtin_amdgcn_global_load_lds((const __attribute__((address_space(1))) void*)g,
                                   (__attribute__((address_space(3))) void*)l, 16, 0, 0);
}

// ---------------- GEMM: C[M,N] = A[M,K] @ W[N,K]^T + bias, optional relu ----
// OMODE: 0 = f32 out, 1 = bf16 out, 2 = both.  M%128==0, N%128==0, K%32==0.
template <int OMODE, bool RELU>
__global__ __launch_bounds__(256) void gemm_bt(
    const bf16* __restrict__ A, const bf16* __restrict__ W,
    const float* __restrict__ bias, float* __restrict__ Cf,
    bf16* __restrict__ Cb, int M, int N, int K) {
  __shared__ bf16 As[128 * 32];
  __shared__ bf16 Bs[128 * 32];
  const int tid = threadIdx.x;
  const int wave = tid >> 6, lane = tid & 63;
  const int m0 = blockIdx.x * 128, n0 = blockIdx.y * 128;
  const int wm = (wave >> 1) * 64, wn = (wave & 1) * 64;
  const int lr = lane >> 4, lc = lane & 15;

  f32x4 acc[4][4];
#pragma unroll
  for (int i = 0; i < 4; ++i)
#pragma unroll
    for (int j = 0; j < 4; ++j) acc[i][j] = (f32x4){0.f, 0.f, 0.f, 0.f};

  for (int k0 = 0; k0 < K; k0 += 32) {
#pragma unroll
    for (int j = 0; j < 2; ++j) {
      const int c = (wave * 2 + j) * 64 + lane;     // chunk 0..511
      const int row = c >> 2, kq = (c & 3) * 8;     // 4 chunks/row of 64B
      gload16(A + (size_t)(m0 + row) * K + k0 + kq, (char*)As + (size_t)(wave * 2 + j) * 1024);
      gload16(W + (size_t)(n0 + row) * K + k0 + kq, (char*)Bs + (size_t)(wave * 2 + j) * 1024);
    }
    __syncthreads();  // drains global_load_lds (vmcnt0 before barrier)
    bf16x8 af[4], bv[4];
#pragma unroll
    for (int mi = 0; mi < 4; ++mi)
      af[mi] = *(const bf16x8*)(As + (wm + mi * 16 + lc) * 32 + lr * 8);
#pragma unroll
    for (int ni = 0; ni < 4; ++ni)
      bv[ni] = *(const bf16x8*)(Bs + (wn + ni * 16 + lc) * 32 + lr * 8);
#pragma unroll
    for (int mi = 0; mi < 4; ++mi)
#pragma unroll
      for (int ni = 0; ni < 4; ++ni)
        acc[mi][ni] = __builtin_amdgcn_mfma_f32_16x16x32_bf16(af[mi], bv[ni], acc[mi][ni], 0, 0, 0);
    __syncthreads();
  }

#pragma unroll
  for (int mi = 0; mi < 4; ++mi)
#pragma unroll
    for (int ni = 0; ni < 4; ++ni) {
      const int col = n0 + wn + ni * 16 + lc;
      const float bb = bias[col];
#pragma unroll
      for (int i = 0; i < 4; ++i) {
        const int row = m0 + wm + mi * 16 + lr * 4 + i;
        float v = acc[mi][ni][i] + bb;
        if (RELU) v = fmaxf(v, 0.f);
        if constexpr (OMODE == 0 || OMODE == 2) Cf[(size_t)row * N + col] = v;
        if constexpr (OMODE == 1 || OMODE == 2) Cb[(size_t)row * N + col] = f2bf(v);
      }
    }
}

// ---------------- LayerNorm (one block per row) -----------------------------
template <int DIM, bool RES, bool OUTBF>
__global__ __launch_bounds__(256) void ln_kernel(
    const float* __restrict__ X, const float* __restrict__ R,
    const float* __restrict__ g, const float* __restrict__ bt,
    bf16* __restrict__ ob, float* __restrict__ of) {
  constexpr int PT = DIM / 1024;  // float4s per thread
  const int row = blockIdx.x, tid = threadIdx.x;
  const float4* xr = (const float4*)(X + (size_t)row * DIM);
  float4 v[PT];
  float s = 0.f, sq = 0.f;
#pragma unroll
  for (int j = 0; j < PT; ++j) {
    v[j] = xr[tid + j * 256];
    if constexpr (RES) {
      const float4 r4 = ((const float4*)(R + (size_t)row * DIM))[tid + j * 256];
      v[j].x += r4.x; v[j].y += r4.y; v[j].z += r4.z; v[j].w += r4.w;
    }
    s += v[j].x + v[j].y + v[j].z + v[j].w;
    sq += v[j].x * v[j].x + v[j].y * v[j].y + v[j].z * v[j].z + v[j].w * v[j].w;
  }
#pragma unroll
  for (int o = 32; o; o >>= 1) { s += __shfl_down(s, o); sq += __shfl_down(sq, o); }
  __shared__ float red[8];
  const int wave = tid >> 6, lane = tid & 63;
  if (!lane) { red[wave] = s; red[wave + 4] = sq; }
  __syncthreads();
  s = red[0] + red[1] + red[2] + red[3];
  sq = red[4] + red[5] + red[6] + red[7];
  const float mean = s * (1.f / DIM);
  const float var = sq * (1.f / DIM) - mean * mean;
  const float rs = rsqrtf(var + 1e-5f);
#pragma unroll
  for (int j = 0; j < PT; ++j) {
    const int c = (tid + j * 256) * 4;
    const float o0 = (v[j].x - mean) * rs * g[c + 0] + bt[c + 0];
    const float o1 = (v[j].y - mean) * rs * g[c + 1] + bt[c + 1];
    const float o2 = (v[j].z - mean) * rs * g[c + 2] + bt[c + 2];
    const float o3 = (v[j].w - mean) * rs * g[c + 3] + bt[c + 3];
    if constexpr (OUTBF) {
      union { bf16 h[4]; uint2 u; } t;
      t.h[0] = f2bf(o0); t.h[1] = f2bf(o1); t.h[2] = f2bf(o2); t.h[3] = f2bf(o3);
      ((uint2*)(ob + (size_t)row * DIM))[tid + j * 256] = t.u;
    } else {
      float4 w4 = {o0, o1, o2, o3};
      ((float4*)(of + (size_t)row * DIM))[tid + j * 256] = w4;
    }
  }
}

// ---------------- RoPE ------------------------------------------------------
__global__ __launch_bounds__(256) void rope_tables(float* __restrict__ cT,
                                                   float* __restrict__ sT) {
  const int idx = blockIdx.x * 256 + threadIdx.x;
  if (idx >= NT * NHD) return;
  const int t = idx >> 7, d = idx & 127;
  const float inv = powf(10000.f, -(float)(d & 63) / 64.f);
  const float f = (float)t * inv;
  cT[idx] = cosf(f);
  sT[idx] = sinf(f);
}

// RoPE on the fused qkv buffer [M][3072]: q at col 0, ks at col 1024.
__global__ __launch_bounds__(256) void rope_apply2(bf16* __restrict__ qkv,
                                                   const float* __restrict__ cT,
                                                   const float* __restrict__ sT) {
  const int idx = blockIdx.x * 256 + threadIdx.x;  // pair index
  const int i = idx & 63;
  const int hh = (idx >> 6) & 7;
  const int row = idx >> 9;       // b*T + t
  const int t = row & (NT - 1);
  const size_t off = (size_t)row * 3072 + hh * NHD + i * 2;
  const float c0 = cT[t * NHD + 2 * i], c1 = cT[t * NHD + 2 * i + 1];
  const float s0 = sT[t * NHD + 2 * i], s1 = sT[t * NHD + 2 * i + 1];
  union P2 { unsigned u; bf16 h[2]; };
  P2 a, o;
  a.u = *(const unsigned*)(qkv + off);
  float x0 = bf2f(a.h[0]), x1 = bf2f(a.h[1]);
  o.h[0] = f2bf(x0 * c0 - x1 * s0);
  o.h[1] = f2bf(x1 * c1 + x0 * s1);
  *(unsigned*)(qkv + off) = o.u;
  a.u = *(const unsigned*)(qkv + off + 1024);
  x0 = bf2f(a.h[0]); x1 = bf2f(a.h[1]);
  o.h[0] = f2bf(x0 * c0 - x1 * s0);
  o.h[1] = f2bf(x1 * c1 + x0 * s1);
  *(unsigned*)(qkv + off + 1024) = o.u;
}

// ---------------- MFMA flash attention (fused-buffer inputs) -----------------
// qkv: [M][3072] (q|ks|vs), kava: [NB*2][2048] (ka|va), ktvt: [NB*64][2048].
// In every region, V = K base + 1024.
__global__ __launch_bounds__(256) void attn_mfma(
    const bf16* __restrict__ qkv, const bf16* __restrict__ kava,
    const bf16* __restrict__ ktvt, const float* __restrict__ gate, int layer,
    bf16* __restrict__ out) {
  __shared__ char Ks[64 * 256];    // K tile, row=key (256B), swizzled
  __shared__ char Vts[128 * 128];  // V^T tile, row=d (128B), swizzled
  __shared__ bf16 Pl[4][16][72];   // per-wave P tile, row=q, padded to 144B
  const int tid = threadIdx.x;
  const int w = tid >> 6, lane = tid & 63;
  const int lr = lane >> 4, lc = lane & 15;
  const int bid = blockIdx.x;
  const int qc = bid & 3, h = (bid >> 2) & 7, b = bid >> 5;
  const int q0 = qc * 64 + w * 16;
  const float gv = tanhf(gate[layer]);
  const float scale = 0.08838834764831845f;  // 1/sqrt(128)

  // Q fragments (16 rows x 128 d), A-layout: row=lc, k-chunk=lr*8
  bf16x8 af[4];
#pragma unroll
  for (int ks_ = 0; ks_ < 4; ++ks_)
    af[ks_] = *(const bf16x8*)(qkv + (size_t)(b * NT + q0 + lc) * 3072 + h * NHD +
                               ks_ * 32 + lr * 8);

  f32x4 o[8];
#pragma unroll
  for (int n2 = 0; n2 < 8; ++n2) o[n2] = (f32x4){0.f, 0.f, 0.f, 0.f};
  float m_[4] = {-1e30f, -1e30f, -1e30f, -1e30f};
  float l_[4] = {0.f, 0.f, 0.f, 0.f};

  for (int kb = 0; kb < 6; ++kb) {
    // ---- cooperative stage: K -> Ks (swizzled), V -> Vts (transposed+swz) --
#pragma unroll
    for (int i = 0; i < 4; ++i) {
      const int c = tid + i * 256;
      const int key = c >> 4, d0 = (c & 15) * 8;
      const int gk = kb * 64 + key;
      const bf16* ksrc;
      if (gk < 256)
        ksrc = qkv + (size_t)(b * NT + gk) * 3072 + 1024 + h * NHD + d0;
      else if (gk < 258)
        ksrc = kava + (size_t)(b * 2 + (gk - 256)) * 2048 + h * NHD + d0;
      else if (gk < NKEYS)
        ksrc = ktvt + (size_t)(b * NKT + (gk - 258)) * 2048 + h * NHD + d0;
      else  // pad: any finite data (self key 0), scores masked below
        ksrc = qkv + (size_t)(b * NT) * 3072 + 1024 + h * NHD + d0;
      const uint4 kv_ = *(const uint4*)ksrc;
      const uint4 vv_ = *(const uint4*)(ksrc + 1024);
      *(uint4*)(Ks + key * 256 + ((d0 * 2) ^ ((key & 7) << 4))) = kv_;
      union { uint4 u; bf16 hh[8]; } t;
      t.u = vv_;
#pragma unroll
      for (int j = 0; j < 8; ++j) {
        const int d = d0 + j;
        *(bf16*)(Vts + d * 128 + ((key * 2) ^ ((d & 7) << 4))) = t.hh[j];
      }
    }
    __syncthreads();

    // ---- S = Q K^T for this tile: 4 key sub-tiles x 4 k-steps --------------
    f32x4 s_[4];
#pragma unroll
    for (int n = 0; n < 4; ++n) s_[n] = (f32x4){0.f, 0.f, 0.f, 0.f};
#pragma unroll
    for (int n = 0; n < 4; ++n) {
      const int row = n * 16 + lc;
#pragma unroll
      for (int ks_ = 0; ks_ < 4; ++ks_) {
        const bf16x8 bk =
            *(const bf16x8*)(Ks + row * 256 + ((ks_ * 64 + lr * 16) ^ ((row & 7) << 4)));
        s_[n] = __builtin_amdgcn_mfma_f32_16x16x32_bf16(af[ks_], bk, s_[n], 0, 0, 0);
      }
    }
    // scale + gate + pad mask (col = lc per C-layout)
#pragma unroll
    for (int n = 0; n < 4; ++n) {
      const int gk = kb * 64 + n * 16 + lc;
      const float f = scale * (gk >= 258 ? gv : 1.f);
#pragma unroll
      for (int i = 0; i < 4; ++i)
        s_[n][i] = (gk >= NKEYS) ? -1e30f : s_[n][i] * f;
    }

    // ---- online softmax: row r = lr*4+i, 16-lane butterfly over cols -------
    float corr[4];
#pragma unroll
    for (int i = 0; i < 4; ++i) {
      float mx = fmaxf(fmaxf(s_[0][i], s_[1][i]), fmaxf(s_[2][i], s_[3][i]));
#pragma unroll
      for (int off = 8; off; off >>= 1) mx = fmaxf(mx, __shfl_xor(mx, off));
      const float mnew = fmaxf(m_[i], mx);
      corr[i] = __expf(m_[i] - mnew);
      m_[i] = mnew;
      float rs = 0.f;
#pragma unroll
      for (int n = 0; n < 4; ++n) {
        const float p = __expf(s_[n][i] - mnew);
        s_[n][i] = p;
        rs += p;
      }
#pragma unroll
      for (int off = 8; off; off >>= 1) rs += __shfl_xor(rs, off);
      l_[i] = l_[i] * corr[i] + rs;
#pragma unroll
      for (int n = 0; n < 4; ++n) Pl[w][lr * 4 + i][n * 16 + lc] = f2bf(s_[n][i]);
    }
#pragma unroll
    for (int n2 = 0; n2 < 8; ++n2)
#pragma unroll
      for (int i = 0; i < 4; ++i) o[n2][i] *= corr[i];

    // wave-local ds_write -> ds_read ordering for Pl
    asm volatile("s_waitcnt lgkmcnt(0)" ::: "memory");

    // ---- O += P V : A = P[16q x 64k], B = V^T[d][k] ------------------------
    const bf16x8 pa0 = *(const bf16x8*)(&Pl[w][lc][lr * 8]);
    const bf16x8 pa1 = *(const bf16x8*)(&Pl[w][lc][32 + lr * 8]);
#pragma unroll
    for (int n2 = 0; n2 < 8; ++n2) {
      const int row = n2 * 16 + lc;
      const bf16x8 bv0 =
          *(const bf16x8*)(Vts + row * 128 + ((lr * 16) ^ ((row & 7) << 4)));
      const bf16x8 bv1 =
          *(const bf16x8*)(Vts + row * 128 + ((64 + lr * 16) ^ ((row & 7) << 4)));
      o[n2] = __builtin_amdgcn_mfma_f32_16x16x32_bf16(pa0, bv0, o[n2], 0, 0, 0);
      o[n2] = __builtin_amdgcn_mfma_f32_16x16x32_bf16(pa1, bv1, o[n2], 0, 0, 0);
    }
    __syncthreads();
  }

  // ---- epilogue: O /= l, write bf16 ----------------------------------------
#pragma unroll
  for (int i = 0; i < 4; ++i) {
    const float inv = 1.f / l_[i];
    bf16* op = out + (size_t)(b * NT + q0 + lr * 4 + i) * NHID + h * NHD;
#pragma unroll
    for (int n2 = 0; n2 < 8; ++n2) op[n2 * 16 + lc] = f2bf(o[n2][i] * inv);
  }
}

// ---------------- Final 12-wide head ---------------------------------------
__global__ __launch_bounds__(256) void head_kernel(const float* __restrict__ lnf,
                                                   const float* __restrict__ W2,
                                                   const float* __restrict__ b2,
                                                   float* __restrict__ out) {
  __shared__ float4 xs[4096];  // [c4][row] transposed: 16 rows x 1024
  const int r0 = blockIdx.x * 16;
  const float4* src = (const float4*)(lnf + (size_t)r0 * NHID);
  for (int e = threadIdx.x; e < 4096; e += 256) {
    const int row = e >> 8, c4 = e & 255;
    xs[c4 * 16 + row] = src[e];
  }
  __syncthreads();
  if (threadIdx.x < 192) {
    const int rr = threadIdx.x / 12, n = threadIdx.x % 12;
    const float4* w4 = (const float4*)(W2 + (size_t)n * NHID);
    float s = b2[n];
    for (int k = 0; k < 256; ++k) {
      const float4 a = xs[k * 16 + rr], w = w4[k];
      s += a.x * w.x + a.y * w.y + a.z * w.z + a.w * w.w;
    }
    out[(size_t)(r0 + rr) * NOUT + n] = s;
  }
}

// ---------------- conversions / packing -------------------------------------
__global__ __launch_bounds__(256) void cvt_f32_bf16(const float* __restrict__ in,
                                                    bf16* __restrict__ o, int n4) {
  const int i = blockIdx.x * 256 + threadIdx.x;
  if (i >= n4) return;
  const float4 v = ((const float4*)in)[i];
  union { bf16 h[4]; uint2 u; } t;
  t.h[0] = f2bf(v.x); t.h[1] = f2bf(v.y); t.h[2] = f2bf(v.z); t.h[3] = f2bf(v.w);
  ((uint2*)o)[i] = t.u;
}

// dst[l][per] from up to 3 [NLAYER][1024] bias arrays (per = 2048 or 3072)
__global__ __launch_bounds__(256) void pack_bias(const float* __restrict__ a,
                                                 const float* __restrict__ b,
                                                 const float* __restrict__ c,
                                                 float* __restrict__ dst, int per) {
  const int idx = blockIdx.x * 256 + threadIdx.x;
  if (idx >= NLAYER * per) return;
  const int l = idx / per, j = idx % per;
  const int sel = j >> 10;
  const float* src = (sel == 0) ? a : (sel == 1) ? b : c;
  dst[idx] = src[l * 1024 + (j & 1023)];
}

__global__ __launch_bounds__(256) void cvt_ht(const float* __restrict__ ht, int layer,
                                              bf16* __restrict__ o) {
  const int i = blockIdx.x * 256 + threadIdx.x;  // n4 = NB*NKT*NHID/4
  if (i >= NB * NKT * NHID / 4) return;
  const int c4 = i & 255;
  const int s = (i >> 8) & 63;
  const int bb = i >> 14;
  const float4 v =
      ((const float4*)(ht + ((size_t)((bb * NLAYER + layer) * NKT + s)) * NHID))[c4];
  union { bf16 h[4]; uint2 u; } t;
  t.h[0] = f2bf(v.x); t.h[1] = f2bf(v.y); t.h[2] = f2bf(v.z); t.h[3] = f2bf(v.w);
  ((uint2*)o)[i] = t.u;
}

__global__ __launch_bounds__(256) void build_had(const float* __restrict__ ha,
                                                 const float* __restrict__ p, int layer,
                                                 bf16* __restrict__ o) {
  const int i = blockIdx.x * 256 + threadIdx.x;  // n4 = NB*2*NHID/4
  if (i >= NB * 2 * NHID / 4) return;
  const int c4 = i & 255;
  const int s = (i >> 8) & 1;
  const int bb = i >> 9;
  const float* base = s ? (p + (size_t)bb * NHID) : (ha + (size_t)(bb * NLAYER + layer) * NHID);
  const float4 v = ((const float4*)base)[c4];
  union { bf16 h[4]; uint2 u; } t;
  t.h[0] = f2bf(v.x); t.h[1] = f2bf(v.y); t.h[2] = f2bf(v.z); t.h[3] = f2bf(v.w);
  ((uint2*)o)[i] = t.u;
}

// ---------------- host ------------------------------------------------------
extern "C" void kernel_launch(void* const* d_in, const int* in_sizes, int n_in,
                              void* d_out, int out_size, void* d_ws, size_t ws_size,
                              hipStream_t stream) {
  const float* x = (const float*)d_in[0];
  const float* h_a = (const float*)d_in[1];
  const float* h_t = (const float*)d_in[2];
  const float* p = (const float*)d_in[3];
  const float* ln1g = (const float*)d_in[4];
  const float* ln1b = (const float*)d_in[5];
  const float* W1 = (const float*)d_in[6];
  const float* b1 = (const float*)d_in[7];
  const float* Wq = (const float*)d_in[8];
  const float* bq = (const float*)d_in[9];
  const float* Wks = (const float*)d_in[10];
  const float* bks = (const float*)d_in[11];
  const float* Wvs = (const float*)d_in[12];
  const float* bvs = (const float*)d_in[13];
  const float* Wka = (const float*)d_in[14];
  const float* bka = (const float*)d_in[15];
  const float* Wva = (const float*)d_in[16];
  const float* bva = (const float*)d_in[17];
  const float* Wkt = (const float*)d_in[18];
  const float* bkt = (const float*)d_in[19];
  const float* Wvt = (const float*)d_in[20];
  const float* bvt = (const float*)d_in[21];
  const float* Wo = (const float*)d_in[22];
  const float* bo = (const float*)d_in[23];
  const float* gate = (const float*)d_in[24];
  const float* flng = (const float*)d_in[25];
  const float* flnb = (const float*)d_in[26];
  const float* Wf = (const float*)d_in[27];
  const float* bff = (const float*)d_in[28];
  const float* ln2g = (const float*)d_in[29];
  const float* ln2b = (const float*)d_in[30];
  const float* W2 = (const float*)d_in[31];
  const float* b2 = (const float*)d_in[32];

  char* wsp = (char*)d_ws;
  size_t off = 0;
  auto alloc = [&](size_t bytes) -> void* {
    void* rp = wsp + off;
    off = (off + bytes + 255) & ~(size_t)255;
    return rp;
  };
  const size_t MT = (size_t)NB * NT;   // 16384 rows
  const size_t WSZ = (size_t)NHID * NHID;  // 1M elements per weight matrix

  bf16* W1b = (bf16*)alloc((size_t)NHID * NIN * 2);
  bf16* Wqkvb = (bf16*)alloc((size_t)NLAYER * 3 * WSZ * 2);   // [L][3072][1024]
  bf16* Wktvtb = (bf16*)alloc((size_t)NLAYER * 2 * WSZ * 2);  // [L][2048][1024]
  bf16* Wkavab = (bf16*)alloc((size_t)NLAYER * 2 * WSZ * 2);  // [L][2048][1024]
  bf16* Wob = (bf16*)alloc((size_t)NLAYER * WSZ * 2);
  bf16* Wfb = (bf16*)alloc((size_t)NLAYER * WSZ * 2);
  float* bqkv = (float*)alloc((size_t)NLAYER * 3072 * 4);
  float* bktvt = (float*)alloc((size_t)NLAYER * 2048 * 4);
  float* bkava = (float*)alloc((size_t)NLAYER * 2048 * 4);
  float* ropeC = (float*)alloc((size_t)NT * NHD * 4);
  float* ropeS = (float*)alloc((size_t)NT * NHD * 4);
  float* hF = (float*)alloc(MT * NHID * 4);
  bf16* hB = (bf16*)alloc(MT * NHID * 2);
  bf16* regA = (bf16*)alloc(MT * NIN * 2);   // h0bf; later qkvC (96MB) + atB (32MB)
  float* oF = (float*)alloc(MT * NHID * 4);  // Wo out, later LN2 f32 out
  bf16* lnB = (bf16*)alloc(MT * NHID * 2);
  bf16* htiB = (bf16*)alloc((size_t)NB * NKT * NHID * 2);
  bf16* ktvtC = (bf16*)alloc((size_t)NB * NKT * 2048 * 2);
  bf16* hadB = (bf16*)alloc((size_t)NB * 2 * NHID * 2);
  bf16* kavaC = (bf16*)alloc((size_t)NB * 2 * 2048 * 2);
  if (off > ws_size) {
    fprintf(stderr, "kernel_launch: ws too small (need %zu, have %zu)\n", off, ws_size);
    return;
  }

  bf16* h0b = regA;
  bf16* qkvC = regA;                       // [MT][3072]
  bf16* atB = regA + MT * 3072;            // [MT][1024]

  // ---- weights -> bf16 (fused layouts) ----
  cvt_f32_bf16<<<(NHID * NIN / 4) / 256, 256, 0, stream>>>(W1, W1b, NHID * NIN / 4);
  const int m4 = (int)(WSZ / 4);  // float4s per matrix -> 1024 blocks
  for (int l = 0; l < NLAYER; ++l) {
    cvt_f32_bf16<<<m4 / 256, 256, 0, stream>>>(Wq + l * WSZ, Wqkvb + (size_t)l * 3 * WSZ, m4);
    cvt_f32_bf16<<<m4 / 256, 256, 0, stream>>>(Wks + l * WSZ, Wqkvb + (size_t)l * 3 * WSZ + WSZ, m4);
    cvt_f32_bf16<<<m4 / 256, 256, 0, stream>>>(Wvs + l * WSZ, Wqkvb + (size_t)l * 3 * WSZ + 2 * WSZ, m4);
    cvt_f32_bf16<<<m4 / 256, 256, 0, stream>>>(Wkt + l * WSZ, Wktvtb + (size_t)l * 2 * WSZ, m4);
    cvt_f32_bf16<<<m4 / 256, 256, 0, stream>>>(Wvt + l * WSZ, Wktvtb + (size_t)l * 2 * WSZ + WSZ, m4);
    cvt_f32_bf16<<<m4 / 256, 256, 0, stream>>>(Wka + l * WSZ, Wkavab + (size_t)l * 2 * WSZ, m4);
    cvt_f32_bf16<<<m4 / 256, 256, 0, stream>>>(Wva + l * WSZ, Wkavab + (size_t)l * 2 * WSZ + WSZ, m4);
    cvt_f32_bf16<<<m4 / 256, 256, 0, stream>>>(Wo + l * WSZ, Wob + (size_t)l * WSZ, m4);
    cvt_f32_bf16<<<m4 / 256, 256, 0, stream>>>(Wf + l * WSZ, Wfb + (size_t)l * WSZ, m4);
  }
  pack_bias<<<(NLAYER * 3072 + 255) / 256, 256, 0, stream>>>(bq, bks, bvs, bqkv, 3072);
  pack_bias<<<(NLAYER * 2048 + 255) / 256, 256, 0, stream>>>(bkt, bvt, nullptr, bktvt, 2048);
  pack_bias<<<(NLAYER * 2048 + 255) / 256, 256, 0, stream>>>(bka, bva, nullptr, bkava, 2048);
  rope_tables<<<(NT * NHD + 255) / 256, 256, 0, stream>>>(ropeC, ropeS);

  // stage 1: LN1 -> W1 (relu)
  ln_kernel<NIN, false, true><<<MT, 256, 0, stream>>>(x, nullptr, ln1g, ln1b, h0b, nullptr);
  gemm_bt<2, true><<<dim3(MT / 128, NHID / 128), 256, 0, stream>>>(
      h0b, W1b, b1, hF, hB, (int)MT, NHID, NIN);

  for (int li = 0; li < NLAYER; ++li) {
    build_had<<<(NB * 2 * NHID / 4) / 256, 256, 0, stream>>>(h_a, p, li, hadB);
    cvt_ht<<<(NB * NKT * NHID / 4) / 256, 256, 0, stream>>>(h_t, li, htiB);
    // fused q|ks|vs: N = 3072, grid 128x24 = 3072 blocks
    gemm_bt<1, false><<<dim3(MT / 128, 24), 256, 0, stream>>>(
        hB, Wqkvb + (size_t)li * 3 * WSZ, bqkv + li * 3072, nullptr, qkvC,
        (int)MT, 3072, NHID);
    // fused kt|vt: N = 2048, grid 32x16
    gemm_bt<1, false><<<dim3(NB * NKT / 128, 16), 256, 0, stream>>>(
        htiB, Wktvtb + (size_t)li * 2 * WSZ, bktvt + li * 2048, nullptr, ktvtC,
        NB * NKT, 2048, NHID);
    // fused ka|va: N = 2048, grid 1x16
    gemm_bt<1, false><<<dim3(1, 16), 256, 0, stream>>>(
        hadB, Wkavab + (size_t)li * 2 * WSZ, bkava + li * 2048, nullptr, kavaC,
        NB * 2, 2048, NHID);
    rope_apply2<<<(int)(MT * NHID / 2 / 256), 256, 0, stream>>>(qkvC, ropeC, ropeS);
    attn_mfma<<<NB * NHEAD * 4, 256, 0, stream>>>(qkvC, kavaC, ktvtC, gate, li, atB);
    gemm_bt<0, false><<<dim3(MT / 128, 8), 256, 0, stream>>>(
        atB, Wob + (size_t)li * WSZ, bo + li * NHID, oF, nullptr, (int)MT, NHID, NHID);
    ln_kernel<NHID, true, true><<<MT, 256, 0, stream>>>(
        oF, hF, flng + li * NHID, flnb + li * NHID, lnB, nullptr);
    gemm_bt<2, true><<<dim3(MT / 128, 8), 256, 0, stream>>>(
        lnB, Wfb + (size_t)li * WSZ, bff + li * NHID, hF, hB, (int)MT, NHID, NHID);
  }

  // final LN (f32 out for precision) + 12-wide head
  ln_kernel<NHID, false, false><<<MT, 256, 0, stream>>>(hF, nullptr, ln2g, ln2b, nullptr, oF);
  head_kernel<<<MT / 16, 256, 0, stream>>>(oF, W2, b2, (float*)d_out);
}